// Round 2
// baseline (520.334 us; speedup 1.0000x reference)
//
#include <hip/hip_runtime.h>
#include <hip/hip_bf16.h>
#include <stdint.h>

typedef __bf16 bf16;
typedef __bf16 bf16x8 __attribute__((ext_vector_type(8)));
typedef float floatx16 __attribute__((ext_vector_type(16)));

// fp32 -> bf16 cast, 8 elements/thread. n % 8 == 0.
__global__ __launch_bounds__(256) void cast_f32_bf16(
    const float* __restrict__ in, bf16* __restrict__ out, int n)
{
    int i = (blockIdx.x * 256 + threadIdx.x) * 8;
    if (i >= n) return;
    float4 a = *(const float4*)(in + i);
    float4 b = *(const float4*)(in + i + 4);
    bf16x8 o;
    o[0] = (bf16)a.x; o[1] = (bf16)a.y; o[2] = (bf16)a.z; o[3] = (bf16)a.w;
    o[4] = (bf16)b.x; o[5] = (bf16)b.y; o[6] = (bf16)b.z; o[7] = (bf16)b.w;
    *(bf16x8*)(out + i) = o;
}

// direct global->LDS, 16 B per lane. LDS dest is wave-uniform base + lane*16
// (per-thread ptr = w*1024B + l*16B decomposes exactly that way). Swizzle is
// applied on the GLOBAL source address and on the read side (rule 21).
__device__ __forceinline__ void load_lds16(const bf16* g, bf16* l) {
    __builtin_amdgcn_global_load_lds(
        (const __attribute__((address_space(1))) void*)g,
        (__attribute__((address_space(3))) void*)l, 16, 0, 0);
}

#define VMCNT(N) asm volatile("s_waitcnt vmcnt(" #N ")" ::: "memory")

// C[m,n] = sum_k A[m,k] * Bt[n,k];  A:[M,K] bf16, Bt:[N,K] bf16.
// M%256==0, N%256==0, K%32==0, K/32 >= 4 assumed.
//
// Deep-pipeline structure (R5/R6): 256x256 tile, 8 waves (2Mx4N, wave tile
// 128x64), mfma_32x32x16, global_load_lds staging into a 4-buffer LDS ring,
// 3 K-tiles in flight, counted vmcnt(12) (never 0 in main loop), 2 raw
// s_barriers per K-step with full compiler fences.
// Race-freedom: at iter t, after issuing tile t+3 (4 loads/thread),
// vmcnt(12) retires exactly tile t's loads; barrier A publishes all waves'
// shares; all ds_reads feed MFMAs (compiler lgkm waits) + explicit
// lgkmcnt(0) before barrier B; only after barrier B can any wave issue
// tile t+4 which overwrites buffer t%4. In-flight writes (t+1..t+3) never
// alias the buffer being read (t%4).
// Swizzle: phys chunk p at LDS row r holds logical k-chunk p^((r>>1)&3);
// staging fetches global chunk (t&3)^((t>>3)&3) into linear dest t*16B
// (identical involution both sides; 0 bank conflicts verified in R3/R4).
template <typename CT>
__global__ __launch_bounds__(512, 2) void gemm_bt(
    const bf16* __restrict__ A, const bf16* __restrict__ Bt, CT* __restrict__ C,
    int M, int N, int K)
{
    __shared__ __align__(16) bf16 As[4 * 8192];   // 4 bufs x 256x32  = 64 KiB
    __shared__ __align__(16) bf16 Bs[4 * 8192];   // 4 bufs x 256x32  = 64 KiB

    const int tid = threadIdx.x;
    const int w     = tid >> 6;       // wave 0..7
    const int l     = tid & 63;
    const int wm    = w & 1;          // M half: 128 rows
    const int wn    = w >> 1;         // N quarter: 64 cols
    const int lm32  = l & 31;
    const int lhalf = l >> 5;

    const int mBase = blockIdx.y * 256;
    const int nBase = blockIdx.x * 256;

    // staging geometry: thread t owns linear LDS bytes [t*16, t*16+16) of
    // each 8 KiB half (rows 0..127 / 128..255). row = t>>2, phys chunk =
    // t&3; fetch global logical chunk (t&3)^((t>>3)&3) = phys ^ ((row>>1)&3).
    const int rowT  = tid >> 2;
    const int lchnk = (tid & 3) ^ ((tid >> 3) & 3);
    const int kelm  = lchnk * 8;

    const bf16* gA0 = A  + (size_t)(mBase + rowT) * K + kelm;
    const bf16* gA1 = gA0 + (size_t)128 * K;
    const bf16* gB0 = Bt + (size_t)(nBase + rowT) * K + kelm;
    const bf16* gB1 = gB0 + (size_t)128 * K;

    bf16* lA = As + tid * 8;
    bf16* lB = Bs + tid * 8;

    // fragment read offsets (32x32x16: A/B lane row = l&31, k = (l>>5)*8+j).
    // logical chunk c = ksub*2 + lhalf; phys = c ^ ((row>>1)&3); all row
    // terms except lm32 are ≡ 0 mod 4 after >>1, so swz = (lm32>>1)&3.
    const int swz = (lm32 >> 1) & 3;
    const int fA0 = (wm * 128 + lm32) * 32 + ((0 + lhalf) ^ swz) * 8;
    const int fA1 = (wm * 128 + lm32) * 32 + ((2 + lhalf) ^ swz) * 8;
    const int fB0 = (wn * 64  + lm32) * 32 + ((0 + lhalf) ^ swz) * 8;
    const int fB1 = (wn * 64  + lm32) * 32 + ((2 + lhalf) ^ swz) * 8;

#define STAGE(kt) do {                                   \
        const int _b = ((kt) & 3) * 8192;                \
        const int _o = (kt) * 32;                        \
        load_lds16(gA0 + _o, lA + _b);                   \
        load_lds16(gA1 + _o, lA + _b + 4096);            \
        load_lds16(gB0 + _o, lB + _b);                   \
        load_lds16(gB1 + _o, lB + _b + 4096);            \
    } while (0)

#define KSTEP(tt, NCNT) do {                                              \
        VMCNT(NCNT);                                                      \
        __builtin_amdgcn_s_barrier();                                     \
        asm volatile("" ::: "memory");                                    \
        __builtin_amdgcn_sched_barrier(0);                                \
        const bf16* Ab = As + ((tt) & 3) * 8192;                          \
        const bf16* Bb = Bs + ((tt) & 3) * 8192;                          \
        bf16x8 a0[4], a1[4], b0[2], b1[2];                                \
        _Pragma("unroll")                                                 \
        for (int i = 0; i < 4; ++i) {                                     \
            a0[i] = *(const bf16x8*)(Ab + fA0 + i * 1024);                \
            a1[i] = *(const bf16x8*)(Ab + fA1 + i * 1024);                \
        }                                                                 \
        _Pragma("unroll")                                                 \
        for (int j = 0; j < 2; ++j) {                                     \
            b0[j] = *(const bf16x8*)(Bb + fB0 + j * 1024);                \
            b1[j] = *(const bf16x8*)(Bb + fB1 + j * 1024);                \
        }                                                                 \
        __builtin_amdgcn_s_setprio(1);                                    \
        _Pragma("unroll")                                                 \
        for (int i = 0; i < 4; ++i)                                       \
            _Pragma("unroll")                                             \
            for (int j = 0; j < 2; ++j) {                                 \
                acc[i][j] = __builtin_amdgcn_mfma_f32_32x32x16_bf16(      \
                    a0[i], b0[j], acc[i][j], 0, 0, 0);                    \
                acc[i][j] = __builtin_amdgcn_mfma_f32_32x32x16_bf16(      \
                    a1[i], b1[j], acc[i][j], 0, 0, 0);                    \
            }                                                             \
        __builtin_amdgcn_s_setprio(0);                                    \
        __builtin_amdgcn_sched_barrier(0);                                \
        asm volatile("s_waitcnt lgkmcnt(0)" ::: "memory");                \
        __builtin_amdgcn_sched_barrier(0);                                \
        __builtin_amdgcn_s_barrier();                                     \
        asm volatile("" ::: "memory");                                    \
    } while (0)

    floatx16 acc[4][2] = {};

    // prologue: tiles 0..2 in flight (12 loads/thread)
    STAGE(0); STAGE(1); STAGE(2);

    const int kIters = K / 32;
    int kt = 0;
    for (; kt < kIters - 3; ++kt) {
        STAGE(kt + 3);          // 16 outstanding max
        KSTEP(kt, 12);          // retire tile kt, keep kt+1..kt+3 in flight
    }
    KSTEP(kt, 8); ++kt;         // epilogue drain 12 -> 8 -> 4 -> 0
    KSTEP(kt, 4); ++kt;
    KSTEP(kt, 0);

#undef STAGE
#undef KSTEP

    // C/D layout (32x32): col = lane&31, row = (reg&3) + 8*(reg>>2) + 4*(lane>>5)
    #pragma unroll
    for (int i = 0; i < 4; ++i) {
        #pragma unroll
        for (int j = 0; j < 2; ++j) {
            const int col = nBase + wn * 64 + j * 32 + lm32;
            const int rB  = mBase + wm * 128 + i * 32 + 4 * lhalf;
            #pragma unroll
            for (int r = 0; r < 16; ++r) {
                const int row = rB + (r & 3) + 8 * (r >> 2);
                C[(size_t)row * N + col] = (CT)acc[i][j][r];
            }
        }
    }
}

// BCx: [8192, 6144] bf16 (cols 0:2048=B, 2048:4096=C, 4096:6144=x)
// convw: [2048, 3] fp32;  Y: [8192, 2048] bf16
// y[b,s,h] = C * (w0*Bx[s-2] + w1*Bx[s-1] + w2*Bx[s]),  Bx = B*x, causal.
__global__ __launch_bounds__(256) void conv_gate(
    const bf16* __restrict__ BCx, const float* __restrict__ convw,
    bf16* __restrict__ Y)
{
    const int tx = threadIdx.x;     // 256 threads cover 2048 h, 8 each
    const int h0 = tx * 8;
    const int bb = blockIdx.y;      // batch
    const int s0 = blockIdx.x * 32; // seq chunk

    float w0[8], w1[8], w2[8];
    #pragma unroll
    for (int j = 0; j < 8; ++j) {
        w0[j] = convw[(h0 + j) * 3 + 0];
        w1[j] = convw[(h0 + j) * 3 + 1];
        w2[j] = convw[(h0 + j) * 3 + 2];
    }

    const size_t mB = (size_t)bb * 4096;

    float bx1[8], bx2[8];
    #pragma unroll
    for (int j = 0; j < 8; ++j) { bx1[j] = 0.f; bx2[j] = 0.f; }
    if (s0 >= 2) {
        const bf16* r1 = BCx + (mB + s0 - 1) * 6144;
        const bf16* r2 = BCx + (mB + s0 - 2) * 6144;
        bf16x8 B1 = *(const bf16x8*)(r1 + h0);
        bf16x8 x1 = *(const bf16x8*)(r1 + 4096 + h0);
        bf16x8 B2 = *(const bf16x8*)(r2 + h0);
        bf16x8 x2 = *(const bf16x8*)(r2 + 4096 + h0);
        #pragma unroll
        for (int j = 0; j < 8; ++j) {
            bx1[j] = (float)B1[j] * (float)x1[j];
            bx2[j] = (float)B2[j] * (float)x2[j];
        }
    }

    for (int s = s0; s < s0 + 32; ++s) {
        const size_t m = mB + s;
        const bf16* rp = BCx + m * 6144;
        bf16x8 Bv = *(const bf16x8*)(rp + h0);
        bf16x8 Cv = *(const bf16x8*)(rp + 2048 + h0);
        bf16x8 xv = *(const bf16x8*)(rp + 4096 + h0);
        bf16x8 o;
        #pragma unroll
        for (int j = 0; j < 8; ++j) {
            float bx0 = (float)Bv[j] * (float)xv[j];
            float cv  = w0[j] * bx2[j] + w1[j] * bx1[j] + w2[j] * bx0;
            o[j] = (bf16)((float)Cv[j] * cv);
            bx2[j] = bx1[j];
            bx1[j] = bx0;
        }
        *(bf16x8*)(Y + m * 2048 + h0) = o;
    }
}

extern "C" void kernel_launch(void* const* d_in, const int* in_sizes, int n_in,
                              void* d_out, int out_size, void* d_ws, size_t ws_size,
                              hipStream_t stream) {
    const float* hidden = (const float*)d_in[0];   // [2,4096,2048] fp32
    const float* Win    = (const float*)d_in[1];   // [6144,2048]  fp32 (B^T layout)
    const float* convw  = (const float*)d_in[2];   // [2048,1,3]   fp32
    const float* Wout   = (const float*)d_in[3];   // [2048,2048]  fp32 (B^T layout)
    float* out = (float*)d_out;                    // [8192,2048]  fp32

    const int nH = 8192 * 2048;      // 16,777,216
    const int nWin = 6144 * 2048;    // 12,582,912
    const int nWout = 2048 * 2048;   //  4,194,304

    bf16* hB    = (bf16*)d_ws;                       // 32 MiB
    bf16* WinB  = hB + (size_t)nH;                   // 24 MiB
    bf16* WoutB = WinB + (size_t)nWin;               //  8 MiB
    bf16* BCx   = WoutB + (size_t)nWout;             // 96 MiB
    bf16* Y     = BCx + (size_t)8192 * 6144;         // 32 MiB  (total 192 MiB)

    cast_f32_bf16<<<nH / (256 * 8), 256, 0, stream>>>(hidden, hB, nH);
    cast_f32_bf16<<<nWin / (256 * 8), 256, 0, stream>>>(Win, WinB, nWin);
    cast_f32_bf16<<<nWout / (256 * 8), 256, 0, stream>>>(Wout, WoutB, nWout);

    gemm_bt<bf16><<<dim3(6144 / 256, 8192 / 256), dim3(512), 0, stream>>>(
        hB, WinB, BCx, 8192, 6144, 2048);
    conv_gate<<<dim3(4096 / 32, 2), dim3(256), 0, stream>>>(BCx, convw, Y);
    gemm_bt<float><<<dim3(2048 / 256, 8192 / 256), dim3(512), 0, stream>>>(
        Y, WoutB, out, 8192, 2048, 2048);
}

// Round 3
// 517.760 us; speedup vs baseline: 1.0050x; 1.0050x over previous
//
#include <hip/hip_runtime.h>
#include <hip/hip_bf16.h>
#include <stdint.h>

typedef __bf16 bf16;
typedef __bf16 bf16x8 __attribute__((ext_vector_type(8)));
typedef float floatx16 __attribute__((ext_vector_type(16)));

// fp32 -> bf16 cast, 8 elements/thread. n % 8 == 0.
__global__ __launch_bounds__(256) void cast_f32_bf16(
    const float* __restrict__ in, bf16* __restrict__ out, int n)
{
    int i = (blockIdx.x * 256 + threadIdx.x) * 8;
    if (i >= n) return;
    float4 a = *(const float4*)(in + i);
    float4 b = *(const float4*)(in + i + 4);
    bf16x8 o;
    o[0] = (bf16)a.x; o[1] = (bf16)a.y; o[2] = (bf16)a.z; o[3] = (bf16)a.w;
    o[4] = (bf16)b.x; o[5] = (bf16)b.y; o[6] = (bf16)b.z; o[7] = (bf16)b.w;
    *(bf16x8*)(out + i) = o;
}

// direct global->LDS, 16 B per lane. LDS dest is wave-uniform base + lane*16
// (per-thread ptr = w*1024B + l*16B decomposes exactly that way). Swizzle is
// applied on the GLOBAL source address and on the read side (rule 21).
__device__ __forceinline__ void load_lds16(const bf16* g, bf16* l) {
    __builtin_amdgcn_global_load_lds(
        (const __attribute__((address_space(1))) void*)g,
        (__attribute__((address_space(3))) void*)l, 16, 0, 0);
}

#define VMCNT(N) asm volatile("s_waitcnt vmcnt(" #N ")" ::: "memory")

// C[m,n] = sum_k A[m,k] * Bt[n,k];  A:[M,K] bf16, Bt:[N,K] bf16.
// M%256==0, N%256==0, K%32==0, K/32 >= 4 assumed.
//
// Deep pipeline (R5-R7): 256x256 tile, 8 waves (2Mx4N, wave tile 128x64),
// mfma_32x32x16, global_load_lds into a 4-buffer LDS ring, 3 K-tiles in
// flight, counted vmcnt(12) (never 0 in main loop), 2 raw s_barriers/iter.
//
// R7 swizzle fix: R6 measured 1.887e7 bank conflicts = exactly +4 cyc on
// each of the 4.72e6 ds_read_b128 (MfmaUtil 44->34). Cause: 32x32 frags
// give lanes l and l+32 the SAME row with chunks c and c^1 -> same 16B
// slot pair; half-interleaved LDS phases ({0-3,32-35}) hit 4 slots twice.
// Fix: row-XOR with swapped bits, f(row) = ((row>>1)&1)<<1 | ((row>>2)&1),
// so row-pair parity lands in chunk BIT 1. Verified by enumeration: lanes
// 0-7 -> slots {0,4,2,6,1,5,3,7}; lanes 32-39 -> {1,5,3,7,0,4,2,6};
// groups {0-3,32-35} -> all 8 distinct. Conflict-free under consecutive-8
// and half-interleaved phase models, both k-subtiles.
//
// Race-freedom: at iter t, after issuing tile t+3 (4 loads/thread),
// vmcnt(12) retires exactly tile t's loads; barrier A publishes all waves'
// shares; explicit lgkmcnt(0) before barrier B; only after barrier B can
// any wave issue tile t+4 which overwrites buffer t%4.
template <typename CT>
__global__ __launch_bounds__(512, 2) void gemm_bt(
    const bf16* __restrict__ A, const bf16* __restrict__ Bt, CT* __restrict__ C,
    int M, int N, int K)
{
    __shared__ __align__(16) bf16 As[4 * 8192];   // 4 bufs x 256x32  = 64 KiB
    __shared__ __align__(16) bf16 Bs[4 * 8192];   // 4 bufs x 256x32  = 64 KiB

    const int tid = threadIdx.x;
    const int w     = tid >> 6;       // wave 0..7
    const int l     = tid & 63;
    const int wm    = w & 1;          // M half: 128 rows
    const int wn    = w >> 1;         // N quarter: 64 cols
    const int lm32  = l & 31;
    const int lhalf = l >> 5;

    const int mBase = blockIdx.y * 256;
    const int nBase = blockIdx.x * 256;

    // staging geometry: thread t owns linear LDS bytes [t*16, t*16+16) of
    // each 8 KiB half (rows 0..127 / 128..255). row = t>>2, phys chunk =
    // t&3; fetch global logical chunk p ^ f(row) with
    // f(row) = ((row>>1)&1)<<1 | ((row>>2)&1)  (in tid: (t>>3)&1, (t>>4)&1).
    const int rowT  = tid >> 2;
    const int lchnk = (tid & 3) ^ ((((tid >> 3) & 1) << 1) | ((tid >> 4) & 1));
    const int kelm  = lchnk * 8;

    const bf16* gA0 = A  + (size_t)(mBase + rowT) * K + kelm;
    const bf16* gA1 = gA0 + (size_t)128 * K;
    const bf16* gB0 = Bt + (size_t)(nBase + rowT) * K + kelm;
    const bf16* gB1 = gB0 + (size_t)128 * K;

    bf16* lA = As + tid * 8;
    bf16* lB = Bs + tid * 8;

    // fragment read offsets (32x32x16: lane row = l&31, k = (l>>5)*8 + j).
    // logical chunk c = ksub*2 + lhalf; phys = c ^ f(row). Row terms other
    // than lm32 (128*wm, 64*wn, 32*i/j) vanish in both bits of f, so
    // swz = ((lm32>>1)&1)<<1 | ((lm32>>2)&1).
    const int swz = (((lm32 >> 1) & 1) << 1) | ((lm32 >> 2) & 1);
    const int fA0 = (wm * 128 + lm32) * 32 + ((0 + lhalf) ^ swz) * 8;
    const int fA1 = (wm * 128 + lm32) * 32 + ((2 + lhalf) ^ swz) * 8;
    const int fB0 = (wn * 64  + lm32) * 32 + ((0 + lhalf) ^ swz) * 8;
    const int fB1 = (wn * 64  + lm32) * 32 + ((2 + lhalf) ^ swz) * 8;

#define STAGE(kt) do {                                   \
        const int _b = ((kt) & 3) * 8192;                \
        const int _o = (kt) * 32;                        \
        load_lds16(gA0 + _o, lA + _b);                   \
        load_lds16(gA1 + _o, lA + _b + 4096);            \
        load_lds16(gB0 + _o, lB + _b);                   \
        load_lds16(gB1 + _o, lB + _b + 4096);            \
    } while (0)

#define KSTEP(tt, NCNT) do {                                              \
        VMCNT(NCNT);                                                      \
        __builtin_amdgcn_s_barrier();                                     \
        asm volatile("" ::: "memory");                                    \
        __builtin_amdgcn_sched_barrier(0);                                \
        const bf16* Ab = As + ((tt) & 3) * 8192;                          \
        const bf16* Bb = Bs + ((tt) & 3) * 8192;                          \
        bf16x8 a0[4], a1[4], b0[2], b1[2];                                \
        _Pragma("unroll")                                                 \
        for (int i = 0; i < 4; ++i) {                                     \
            a0[i] = *(const bf16x8*)(Ab + fA0 + i * 1024);                \
            a1[i] = *(const bf16x8*)(Ab + fA1 + i * 1024);                \
        }                                                                 \
        _Pragma("unroll")                                                 \
        for (int j = 0; j < 2; ++j) {                                     \
            b0[j] = *(const bf16x8*)(Bb + fB0 + j * 1024);                \
            b1[j] = *(const bf16x8*)(Bb + fB1 + j * 1024);                \
        }                                                                 \
        __builtin_amdgcn_s_setprio(1);                                    \
        _Pragma("unroll")                                                 \
        for (int i = 0; i < 4; ++i)                                       \
            _Pragma("unroll")                                             \
            for (int j = 0; j < 2; ++j) {                                 \
                acc[i][j] = __builtin_amdgcn_mfma_f32_32x32x16_bf16(      \
                    a0[i], b0[j], acc[i][j], 0, 0, 0);                    \
                acc[i][j] = __builtin_amdgcn_mfma_f32_32x32x16_bf16(      \
                    a1[i], b1[j], acc[i][j], 0, 0, 0);                    \
            }                                                             \
        __builtin_amdgcn_s_setprio(0);                                    \
        __builtin_amdgcn_sched_barrier(0);                                \
        asm volatile("s_waitcnt lgkmcnt(0)" ::: "memory");                \
        __builtin_amdgcn_sched_barrier(0);                                \
        __builtin_amdgcn_s_barrier();                                     \
        asm volatile("" ::: "memory");                                    \
    } while (0)

    floatx16 acc[4][2] = {};

    // prologue: tiles 0..2 in flight (12 loads/thread)
    STAGE(0); STAGE(1); STAGE(2);

    const int kIters = K / 32;
    int kt = 0;
    for (; kt < kIters - 3; ++kt) {
        STAGE(kt + 3);          // 16 outstanding max
        KSTEP(kt, 12);          // retire tile kt, keep kt+1..kt+3 in flight
    }
    KSTEP(kt, 8); ++kt;         // epilogue drain 12 -> 8 -> 4 -> 0
    KSTEP(kt, 4); ++kt;
    KSTEP(kt, 0);

#undef STAGE
#undef KSTEP

    // C/D layout (32x32): col = lane&31, row = (reg&3) + 8*(reg>>2) + 4*(lane>>5)
    #pragma unroll
    for (int i = 0; i < 4; ++i) {
        #pragma unroll
        for (int j = 0; j < 2; ++j) {
            const int col = nBase + wn * 64 + j * 32 + lm32;
            const int rB  = mBase + wm * 128 + i * 32 + 4 * lhalf;
            #pragma unroll
            for (int r = 0; r < 16; ++r) {
                const int row = rB + (r & 3) + 8 * (r >> 2);
                C[(size_t)row * N + col] = (CT)acc[i][j][r];
            }
        }
    }
}

// BCx: [8192, 6144] bf16 (cols 0:2048=B, 2048:4096=C, 4096:6144=x)
// convw: [2048, 3] fp32;  Y: [8192, 2048] bf16
// y[b,s,h] = C * (w0*Bx[s-2] + w1*Bx[s-1] + w2*Bx[s]),  Bx = B*x, causal.
__global__ __launch_bounds__(256) void conv_gate(
    const bf16* __restrict__ BCx, const float* __restrict__ convw,
    bf16* __restrict__ Y)
{
    const int tx = threadIdx.x;     // 256 threads cover 2048 h, 8 each
    const int h0 = tx * 8;
    const int bb = blockIdx.y;      // batch
    const int s0 = blockIdx.x * 32; // seq chunk

    float w0[8], w1[8], w2[8];
    #pragma unroll
    for (int j = 0; j < 8; ++j) {
        w0[j] = convw[(h0 + j) * 3 + 0];
        w1[j] = convw[(h0 + j) * 3 + 1];
        w2[j] = convw[(h0 + j) * 3 + 2];
    }

    const size_t mB = (size_t)bb * 4096;

    float bx1[8], bx2[8];
    #pragma unroll
    for (int j = 0; j < 8; ++j) { bx1[j] = 0.f; bx2[j] = 0.f; }
    if (s0 >= 2) {
        const bf16* r1 = BCx + (mB + s0 - 1) * 6144;
        const bf16* r2 = BCx + (mB + s0 - 2) * 6144;
        bf16x8 B1 = *(const bf16x8*)(r1 + h0);
        bf16x8 x1 = *(const bf16x8*)(r1 + 4096 + h0);
        bf16x8 B2 = *(const bf16x8*)(r2 + h0);
        bf16x8 x2 = *(const bf16x8*)(r2 + 4096 + h0);
        #pragma unroll
        for (int j = 0; j < 8; ++j) {
            bx1[j] = (float)B1[j] * (float)x1[j];
            bx2[j] = (float)B2[j] * (float)x2[j];
        }
    }

    for (int s = s0; s < s0 + 32; ++s) {
        const size_t m = mB + s;
        const bf16* rp = BCx + m * 6144;
        bf16x8 Bv = *(const bf16x8*)(rp + h0);
        bf16x8 Cv = *(const bf16x8*)(rp + 2048 + h0);
        bf16x8 xv = *(const bf16x8*)(rp + 4096 + h0);
        bf16x8 o;
        #pragma unroll
        for (int j = 0; j < 8; ++j) {
            float bx0 = (float)Bv[j] * (float)xv[j];
            float cv  = w0[j] * bx2[j] + w1[j] * bx1[j] + w2[j] * bx0;
            o[j] = (bf16)((float)Cv[j] * cv);
            bx2[j] = bx1[j];
            bx1[j] = bx0;
        }
        *(bf16x8*)(Y + m * 2048 + h0) = o;
    }
}

extern "C" void kernel_launch(void* const* d_in, const int* in_sizes, int n_in,
                              void* d_out, int out_size, void* d_ws, size_t ws_size,
                              hipStream_t stream) {
    const float* hidden = (const float*)d_in[0];   // [2,4096,2048] fp32
    const float* Win    = (const float*)d_in[1];   // [6144,2048]  fp32 (B^T layout)
    const float* convw  = (const float*)d_in[2];   // [2048,1,3]   fp32
    const float* Wout   = (const float*)d_in[3];   // [2048,2048]  fp32 (B^T layout)
    float* out = (float*)d_out;                    // [8192,2048]  fp32

    const int nH = 8192 * 2048;      // 16,777,216
    const int nWin = 6144 * 2048;    // 12,582,912
    const int nWout = 2048 * 2048;   //  4,194,304

    bf16* hB    = (bf16*)d_ws;                       // 32 MiB
    bf16* WinB  = hB + (size_t)nH;                   // 24 MiB
    bf16* WoutB = WinB + (size_t)nWin;               //  8 MiB
    bf16* BCx   = WoutB + (size_t)nWout;             // 96 MiB
    bf16* Y     = BCx + (size_t)8192 * 6144;         // 32 MiB  (total 192 MiB)

    cast_f32_bf16<<<nH / (256 * 8), 256, 0, stream>>>(hidden, hB, nH);
    cast_f32_bf16<<<nWin / (256 * 8), 256, 0, stream>>>(Win, WinB, nWin);
    cast_f32_bf16<<<nWout / (256 * 8), 256, 0, stream>>>(Wout, WoutB, nWout);

    gemm_bt<bf16><<<dim3(6144 / 256, 8192 / 256), dim3(512), 0, stream>>>(
        hB, WinB, BCx, 8192, 6144, 2048);
    conv_gate<<<dim3(4096 / 32, 2), dim3(256), 0, stream>>>(BCx, convw, Y);
    gemm_bt<float><<<dim3(2048 / 256, 8192 / 256), dim3(512), 0, stream>>>(
        Y, WoutB, out, 8192, 2048, 2048);
}

// Round 4
// 444.390 us; speedup vs baseline: 1.1709x; 1.1651x over previous
//
#include <hip/hip_runtime.h>
#include <hip/hip_bf16.h>
#include <stdint.h>

typedef __bf16 bf16;
typedef __bf16 bf16x8 __attribute__((ext_vector_type(8)));
typedef float floatx4 __attribute__((ext_vector_type(4)));

// fp32 -> bf16 cast, 8 elements/thread. n % 8 == 0.
__global__ __launch_bounds__(256) void cast_f32_bf16(
    const float* __restrict__ in, bf16* __restrict__ out, int n)
{
    int i = (blockIdx.x * 256 + threadIdx.x) * 8;
    if (i >= n) return;
    float4 a = *(const float4*)(in + i);
    float4 b = *(const float4*)(in + i + 4);
    bf16x8 o;
    o[0] = (bf16)a.x; o[1] = (bf16)a.y; o[2] = (bf16)a.z; o[3] = (bf16)a.w;
    o[4] = (bf16)b.x; o[5] = (bf16)b.y; o[6] = (bf16)b.z; o[7] = (bf16)b.w;
    *(bf16x8*)(out + i) = o;
}

__device__ __forceinline__ void load_lds16(const bf16* g, bf16* l) {
    __builtin_amdgcn_global_load_lds(
        (const __attribute__((address_space(1))) void*)g,
        (__attribute__((address_space(3))) void*)l, 16, 0, 0);
}

#define VMCNT(N)  asm volatile("s_waitcnt vmcnt(" #N ")" ::: "memory")
#define LGKM0     do { asm volatile("s_waitcnt lgkmcnt(0)" ::: "memory"); \
                       __builtin_amdgcn_sched_barrier(0); } while (0)
#define BARRIER   do { asm volatile("" ::: "memory");                     \
                       __builtin_amdgcn_s_barrier();                      \
                       asm volatile("" ::: "memory"); } while (0)

// C[m,n] = sum_k A[m,k] * Bt[n,k];  A:[M,K] bf16, Bt:[N,K] bf16.
// M%256==0, N%256==0, K%128==0.
//
// R8: m201-class 8-phase schedule. R5-R7's single-phase ring serialized
// all 8 lockstepped waves into LDS-burst then MFMA-burst (MfmaUtil 34%).
// 8-phase: per K-tile-pair (BK=64 x2), 8 phases; each phase = one C
// quadrant (16x mfma_16x16x32) + one-ahead 4-or-8 ds_read_b128 (Gray
// order: loaded reg-set always dead) + one half-tile global_load_lds
// stage + raw barrier. Counted vmcnt(2)/phase top; loads cross barriers.
// Quadrant order: even tile (A0B0)(A0B1)(A1B1)(A1B0), odd (A0B1)(A0B0)
// (A1B0)(A1B1); reads one phase ahead: e0:B1 e1:A1 e2:A0' e3:B1' o0:B0'
// o1:A1' o2:A0'' o3:B0''. Stage slots (derived; RAW: every read's stage
// retired at prior-phase vmcnt(2)+barrier; WAR: stage >= +1 barrier after
// region's last read): e0:b1.B.h1(o) e1:b0.B.h0(e2) e2:b0.A.h0 e3:b0.A.h1
// o0:b0.B.h1 o1:b1.B.h0(o2) o2:b1.A.h0 o3:b1.A.h1.
// Swizzle (st_16x32): phys chunk = logical ^ (((row>>2)&1)<<1), applied
// on global source (staging) and ds_read addr; LDS dest stays linear.
template <typename CT>
__global__ __launch_bounds__(512, 2) void gemm_bt(
    const bf16* __restrict__ A, const bf16* __restrict__ Bt, CT* __restrict__ C,
    int M, int N, int K)
{
    // [buf][half][128 rows][64 k] bf16 = 64 KiB each
    __shared__ __align__(16) bf16 As[2 * 16384];
    __shared__ __align__(16) bf16 Bs[2 * 16384];

    const int tid = threadIdx.x;
    const int l   = tid & 63;
    const int w   = tid >> 6;
    const int wm  = w & 1;    // M half (128 rows)
    const int wn  = w >> 1;   // N quarter (64 cols)
    const int rl  = l & 15;
    const int kq  = l >> 4;
    const int ck  = (kq ^ (((rl >> 2) & 1) << 1)) * 8;  // swizzled ks=0 chunk

    const int mBase = blockIdx.y * 256;
    const int nBase = blockIdx.x * 256;

    // ds_read bases (elements). A: half=wm, local row=msub*64+i*16+rl.
    const int aRd = wm * 8192 + rl * 64 + ck;
    // B: half=wn>>1, local row=(wn&1)*64+nsub*32+j*16+rl.
    const int bRd = (wn >> 1) * 8192 + ((wn & 1) * 64 + rl) * 64 + ck;

    // staging: thread t owns slot t (row t>>3, phys chunk t&7) and slot
    // t+512 (row +64). Global fetches logical chunk (t&7)^(((t>>5)&1)<<1).
    const int srow = tid >> 3;
    const int schk = (tid & 7) ^ (((tid >> 5) & 1) << 1);
    const bf16* gA = A  + (size_t)(mBase + srow) * K + schk * 8;
    const bf16* gB = Bt + (size_t)(nBase + srow) * K + schk * 8;
    bf16* dA = As + tid * 8;
    bf16* dB = Bs + tid * 8;
    const size_t rowK64 = (size_t)64 * K;

#define STAGE_A(T, h, buf) do {                                           \
        const bf16* _g = gA + (size_t)(h) * 128 * K + (T) * 64;           \
        bf16* _d = dA + (buf) * 16384 + (h) * 8192;                       \
        load_lds16(_g, _d);                                               \
        load_lds16(_g + rowK64, _d + 4096);                               \
    } while (0)
#define STAGE_B(T, h, buf) do {                                           \
        const bf16* _g = gB + (size_t)(h) * 128 * K + (T) * 64;           \
        bf16* _d = dB + (buf) * 16384 + (h) * 8192;                       \
        load_lds16(_g, _d);                                               \
        load_lds16(_g + rowK64, _d + 4096);                               \
    } while (0)

#define READ_A(dst, msub, buf) do {                                       \
        _Pragma("unroll")                                                 \
        for (int _i = 0; _i < 4; ++_i) {                                  \
            _Pragma("unroll")                                             \
            for (int _ks = 0; _ks < 2; ++_ks)                             \
                dst[_i][_ks] = *(const bf16x8*)(As + (buf) * 16384 + aRd  \
                    + (msub) * 4096 + _i * 1024 + _ks * 32);              \
        }                                                                 \
    } while (0)
#define READ_B(dst, nsub, buf) do {                                       \
        _Pragma("unroll")                                                 \
        for (int _j = 0; _j < 2; ++_j) {                                  \
            _Pragma("unroll")                                             \
            for (int _ks = 0; _ks < 2; ++_ks)                             \
                dst[_j][_ks] = *(const bf16x8*)(Bs + (buf) * 16384 + bRd  \
                    + (nsub) * 2048 + _j * 1024 + _ks * 32);              \
        }                                                                 \
    } while (0)

#define MFMA_Q(am, bn, MS, NS) do {                                       \
        __builtin_amdgcn_s_setprio(1);                                    \
        _Pragma("unroll")                                                 \
        for (int _ks = 0; _ks < 2; ++_ks)                                 \
            _Pragma("unroll")                                             \
            for (int _i = 0; _i < 4; ++_i)                                \
                _Pragma("unroll")                                         \
                for (int _j = 0; _j < 2; ++_j)                            \
                    acc[(MS)*4 + _i][(NS)*2 + _j] =                       \
                        __builtin_amdgcn_mfma_f32_16x16x32_bf16(          \
                            am[_i][_ks], bn[_j][_ks],                     \
                            acc[(MS)*4 + _i][(NS)*2 + _j], 0, 0, 0);      \
        __builtin_amdgcn_s_setprio(0);                                    \
    } while (0)

    floatx4 acc[8][4] = {};
    bf16x8 a0[4][2], a1[4][2], b0[2][2], b1[2][2];

    const int kIters = K >> 7;   // pairs of 64-wide K-tiles
    const int nT     = K >> 6;   // 64-wide K-tiles

    // ---- prologue: stages #1..#7 (steady-state issue-order suffix)
    STAGE_B(0, 0, 0);    // #1 buf0.B.h0  (tile 0)
    STAGE_A(0, 0, 0);    // #2 buf0.A.h0
    STAGE_A(0, 1, 0);    // #3 buf0.A.h1
    STAGE_B(0, 1, 0);    // #4 buf0.B.h1
    STAGE_B(1, 0, 1);    // #5 buf1.B.h0  (tile 1)
    STAGE_A(1, 0, 1);    // #6 buf1.A.h0
    STAGE_A(1, 1, 1);    // #7 buf1.A.h1
    VMCNT(2);            // #1..#5 retired (need #1..#4 for reads below)
    BARRIER;
    READ_A(a0, 0, 0);
    READ_B(b0, 0, 0);

    for (int it = 0; it < kIters; ++it) {
        const int To  = 2 * it + 1;
        int Te2 = 2 * it + 2; if (Te2 >= nT) Te2 -= nT;   // wrap: dead data
        int To2 = 2 * it + 3; if (To2 >= nT) To2 -= nT;

        // ph e0: MFMA (A0,B0) of even tile; read B1(e); stage buf1.B.h1(o)
        VMCNT(2); READ_B(b1, 1, 0); STAGE_B(To, 1, 1);
        BARRIER; LGKM0; MFMA_Q(a0, b0, 0, 0);
        // ph e1: MFMA (A0,B1); read A1(e); stage buf0.B.h0(e2)
        VMCNT(2); READ_A(a1, 1, 0); STAGE_B(Te2, 0, 0);
        BARRIER; LGKM0; MFMA_Q(a0, b1, 0, 1);
        // ph e2: MFMA (A1,B1); read A0'(o, buf1); stage buf0.A.h0(e2)
        VMCNT(2); READ_A(a0, 0, 1); STAGE_A(Te2, 0, 0);
        BARRIER; LGKM0; MFMA_Q(a1, b1, 1, 1);
        // ph e3: MFMA (A1,B0); read B1'(o); stage buf0.A.h1(e2)
        VMCNT(2); READ_B(b1, 1, 1); STAGE_A(Te2, 1, 0);
        BARRIER; LGKM0; MFMA_Q(a1, b0, 1, 0);
        // ph o0: MFMA (A0',B1'); read B0'(o); stage buf0.B.h1(e2)
        VMCNT(2); READ_B(b0, 0, 1); STAGE_B(Te2, 1, 0);
        BARRIER; LGKM0; MFMA_Q(a0, b1, 0, 1);
        // ph o1: MFMA (A0',B0'); read A1'(o); stage buf1.B.h0(o2)
        VMCNT(2); READ_A(a1, 1, 1); STAGE_B(To2, 0, 1);
        BARRIER; LGKM0; MFMA_Q(a0, b0, 0, 0);
        // ph o2: MFMA (A1',B0'); read A0''(e2, buf0); stage buf1.A.h0(o2)
        VMCNT(2); READ_A(a0, 0, 0); STAGE_A(To2, 0, 1);
        BARRIER; LGKM0; MFMA_Q(a1, b0, 1, 0);
        // ph o3: MFMA (A1',B1'); read B0''(e2); stage buf1.A.h1(o2)
        VMCNT(2); READ_B(b0, 0, 0); STAGE_A(To2, 1, 1);
        BARRIER; LGKM0; MFMA_Q(a1, b1, 1, 1);
    }

#undef STAGE_A
#undef STAGE_B
#undef READ_A
#undef READ_B
#undef MFMA_Q

    // C/D (16x16): col = lane&15, row = (lane>>4)*4 + reg
    #pragma unroll
    for (int fi = 0; fi < 8; ++fi) {
        #pragma unroll
        for (int fj = 0; fj < 4; ++fj) {
            const int col = nBase + wn * 64 + fj * 16 + rl;
            const int rB  = mBase + wm * 128 + fi * 16 + kq * 4;
            #pragma unroll
            for (int r = 0; r < 4; ++r)
                C[(size_t)(rB + r) * N + col] = (CT)acc[fi][fj][r];
        }
    }
}

// BCx: [8192, 6144] bf16 (cols 0:2048=B, 2048:4096=C, 4096:6144=x)
// convw: [2048, 3] fp32;  Y: [8192, 2048] bf16
// y[b,s,h] = C * (w0*Bx[s-2] + w1*Bx[s-1] + w2*Bx[s]),  Bx = B*x, causal.
__global__ __launch_bounds__(256) void conv_gate(
    const bf16* __restrict__ BCx, const float* __restrict__ convw,
    bf16* __restrict__ Y)
{
    const int tx = threadIdx.x;
    const int h0 = tx * 8;
    const int bb = blockIdx.y;
    const int s0 = blockIdx.x * 32;

    float w0[8], w1[8], w2[8];
    #pragma unroll
    for (int j = 0; j < 8; ++j) {
        w0[j] = convw[(h0 + j) * 3 + 0];
        w1[j] = convw[(h0 + j) * 3 + 1];
        w2[j] = convw[(h0 + j) * 3 + 2];
    }

    const size_t mB = (size_t)bb * 4096;

    float bx1[8], bx2[8];
    #pragma unroll
    for (int j = 0; j < 8; ++j) { bx1[j] = 0.f; bx2[j] = 0.f; }
    if (s0 >= 2) {
        const bf16* r1 = BCx + (mB + s0 - 1) * 6144;
        const bf16* r2 = BCx + (mB + s0 - 2) * 6144;
        bf16x8 B1 = *(const bf16x8*)(r1 + h0);
        bf16x8 x1 = *(const bf16x8*)(r1 + 4096 + h0);
        bf16x8 B2 = *(const bf16x8*)(r2 + h0);
        bf16x8 x2 = *(const bf16x8*)(r2 + 4096 + h0);
        #pragma unroll
        for (int j = 0; j < 8; ++j) {
            bx1[j] = (float)B1[j] * (float)x1[j];
            bx2[j] = (float)B2[j] * (float)x2[j];
        }
    }

    for (int s = s0; s < s0 + 32; ++s) {
        const size_t m = mB + s;
        const bf16* rp = BCx + m * 6144;
        bf16x8 Bv = *(const bf16x8*)(rp + h0);
        bf16x8 Cv = *(const bf16x8*)(rp + 2048 + h0);
        bf16x8 xv = *(const bf16x8*)(rp + 4096 + h0);
        bf16x8 o;
        #pragma unroll
        for (int j = 0; j < 8; ++j) {
            float bx0 = (float)Bv[j] * (float)xv[j];
            float cv  = w0[j] * bx2[j] + w1[j] * bx1[j] + w2[j] * bx0;
            o[j] = (bf16)((float)Cv[j] * cv);
            bx2[j] = bx1[j];
            bx1[j] = bx0;
        }
        *(bf16x8*)(Y + m * 2048 + h0) = o;
    }
}

extern "C" void kernel_launch(void* const* d_in, const int* in_sizes, int n_in,
                              void* d_out, int out_size, void* d_ws, size_t ws_size,
                              hipStream_t stream) {
    const float* hidden = (const float*)d_in[0];   // [2,4096,2048] fp32
    const float* Win    = (const float*)d_in[1];   // [6144,2048]  fp32 (B^T layout)
    const float* convw  = (const float*)d_in[2];   // [2048,1,3]   fp32
    const float* Wout   = (const float*)d_in[3];   // [2048,2048]  fp32 (B^T layout)
    float* out = (float*)d_out;                    // [8192,2048]  fp32

    const int nH = 8192 * 2048;
    const int nWin = 6144 * 2048;
    const int nWout = 2048 * 2048;

    bf16* hB    = (bf16*)d_ws;                       // 32 MiB
    bf16* WinB  = hB + (size_t)nH;                   // 24 MiB
    bf16* WoutB = WinB + (size_t)nWin;               //  8 MiB
    bf16* BCx   = WoutB + (size_t)nWout;             // 96 MiB
    bf16* Y     = BCx + (size_t)8192 * 6144;         // 32 MiB

    cast_f32_bf16<<<nH / (256 * 8), 256, 0, stream>>>(hidden, hB, nH);
    cast_f32_bf16<<<nWin / (256 * 8), 256, 0, stream>>>(Win, WinB, nWin);
    cast_f32_bf16<<<nWout / (256 * 8), 256, 0, stream>>>(Wout, WoutB, nWout);

    gemm_bt<bf16><<<dim3(6144 / 256, 8192 / 256), dim3(512), 0, stream>>>(
        hB, WinB, BCx, 8192, 6144, 2048);
    conv_gate<<<dim3(4096 / 32, 2), dim3(256), 0, stream>>>(BCx, convw, Y);
    gemm_bt<float><<<dim3(2048 / 256, 8192 / 256), dim3(512), 0, stream>>>(
        Y, WoutB, out, 8192, 2048, 2048);
}